// Round 10
// baseline (244.022 us; speedup 1.0000x reference)
//
#include <hip/hip_runtime.h>
#include <hip/hip_bf16.h>
#include <stdint.h>

// Problem constants
constexpr int CB  = 4;     // batch
constexpr int CS  = 2048;  // seq len
constexpr int CH  = 1024;  // hidden
constexpr int CNH = 16;    // heads
constexpr int CDH = 64;    // head dim
constexpr int CM  = CB * CS;  // 8192 rows

typedef __bf16 bf16x8 __attribute__((ext_vector_type(8)));
typedef float  f32x4  __attribute__((ext_vector_type(4)));

// round-to-nearest-even f32 -> bf16 (bit pattern)
__device__ __forceinline__ unsigned short f2bf(float f) {
    union { float f; unsigned u; } c; c.f = f;
    unsigned u = c.u;
    unsigned r = (u + 0x7fffu + ((u >> 16) & 1u)) >> 16;
    return (unsigned short)r;
}

// async global->LDS, 16B per lane. LDS dest = base + lane*16 (wave-uniform base).
__device__ __forceinline__ void gl_lds16(const void* g, void* l) {
    __builtin_amdgcn_global_load_lds((const __attribute__((address_space(1))) uint32_t*)g,
                                     (__attribute__((address_space(3))) uint32_t*)l,
                                     16, 0, 0);
}

__device__ __forceinline__ float fexp2(float x) {
#if __has_builtin(__builtin_amdgcn_exp2f)
    return __builtin_amdgcn_exp2f(x);
#else
    return exp2f(x);
#endif
}

// pack two f32 -> one dword of 2 bf16 (RNE). No builtin on gfx950 (m240) -> asm.
__device__ __forceinline__ unsigned cvtpk_bf16(float lo, float hi) {
    unsigned r;
    asm("v_cvt_pk_bf16_f32 %0, %1, %2" : "=v"(r) : "v"(lo), "v"(hi));
    return r;
}

// a' = [a_r0, a_r1, b_r0, b_r1]; b' = [a_r2, a_r3, b_r2, b_r3]  (16-lane rows)
__device__ __forceinline__ void pl32swap(unsigned &a, unsigned &b) {
#if __has_builtin(__builtin_amdgcn_permlane32_swap)
    auto r = __builtin_amdgcn_permlane32_swap(a, b, false, false);
    a = r[0]; b = r[1];
#else
    int lane = threadIdx.x & 63;
    unsigned as = (unsigned)__shfl((int)a, lane ^ 32);
    unsigned bs = (unsigned)__shfl((int)b, lane ^ 32);
    unsigned na = (lane < 32) ? a : bs;
    unsigned nb = (lane < 32) ? as : b;
    a = na; b = nb;
#endif
}

// a' = [a_r0, b_r0, a_r2, b_r2]; b' = [a_r1, b_r1, a_r3, b_r3]
__device__ __forceinline__ void pl16swap(unsigned &a, unsigned &b) {
#if __has_builtin(__builtin_amdgcn_permlane16_swap)
    auto r = __builtin_amdgcn_permlane16_swap(a, b, false, false);
    a = r[0]; b = r[1];
#else
    unsigned as = __builtin_amdgcn_ds_swizzle(a, 0x401F);  // lane ^ 16 within 32-halves
    unsigned bs = __builtin_amdgcn_ds_swizzle(b, 0x401F);
    int odd = (threadIdx.x >> 4) & 1;
    unsigned na = odd ? bs : a;
    unsigned nb = odd ? b : as;
    a = na; b = nb;
#endif
}

// 1/sqrt(dh) * log2(e): folded into Q at projection time
constexpr float C_SC = 0.125f * 1.44269504f;

// ---------------- fp32 -> bf16 convert (X + 3 weights, one launch) ----------------
// exact 1-D grid: 8192 blocks for X, 1024 per weight; one float4 per thread.
__global__ __launch_bounds__(256) void cvt_all_k(const float* __restrict__ hs,
                                                 const float* __restrict__ w0,
                                                 const float* __restrict__ w1,
                                                 const float* __restrict__ w2,
                                                 unsigned short* __restrict__ Xb,
                                                 unsigned short* __restrict__ Wb) {
    int b = blockIdx.x;
    const float* src; unsigned short* dst; int i;
    if (b < 8192) {
        src = hs; dst = Xb;
        i = b * 256 + (int)threadIdx.x;            // < CM*CH/4 exactly
    } else {
        int t = b - 8192;
        int z = t >> 10;                           // 0,1,2
        src = (z == 0) ? w0 : (z == 1) ? w1 : w2;
        dst = Wb + z * CH * CH;
        i = (t & 1023) * 256 + (int)threadIdx.x;   // < CH*CH/4 exactly
    }
    float4 v = ((const float4*)src)[i];
    ushort4 o;
    o.x = f2bf(v.x); o.y = f2bf(v.y); o.z = f2bf(v.z); o.w = f2bf(v.w);
    ((ushort4*)dst)[i] = o;
}

// ---------------- fused QKV projection GEMM (pipelined + LDS-repacked epilogue) ----
// C[m,n] = sum_k X[m,k] * W[n,k] + bias[n]
// z=0 (Q): out [b,h,s,d], pre-scaled by C_SC. z=1 (K): [b,h,s,d]. z=2 (V): [b,h,d,s].
__global__ __launch_bounds__(256) void qkv_gemm_k(
    const unsigned short* __restrict__ Xb,
    const unsigned short* __restrict__ Wb,
    const float* __restrict__ bq, const float* __restrict__ bk, const float* __restrict__ bv,
    unsigned short* __restrict__ Qo,
    unsigned short* __restrict__ Ko,
    unsigned short* __restrict__ Vt)
{
    // staging (32 KB, double-buffered) and epilogue tile (34 KB) alias the same LDS
    __shared__ alignas(16) unsigned char smem[34816];
    typedef unsigned short (*tile_t)[128][32];
    tile_t As = (tile_t)smem;                 // [2][128][32]
    tile_t Bs = (tile_t)(smem + 16384);       // [2][128][32]
    typedef unsigned short (*ep_t)[136];      // [128][136] (pad -> 16B-aligned rows)
    ep_t Ep = (ep_t)smem;

    const int tid  = threadIdx.x;
    const int wave = tid >> 6, lane = tid & 63;
    const int wm = wave >> 1, wn = wave & 1;
    const int col = lane & 15, quad = lane >> 4;
    const int gm = blockIdx.x * 128, gn = blockIdx.y * 128;
    const int z  = blockIdx.z;
    const unsigned short* W = Wb + (size_t)z * CH * CH;

    f32x4 zero = {0.f, 0.f, 0.f, 0.f};
    f32x4 acc[4][4];
    for (int i = 0; i < 4; i++) for (int j = 0; j < 4; j++) acc[i][j] = zero;

    const int arow = lane >> 2;
    const int acol = (lane & 3) * 8;

    auto stage = [&](int buf, int k0) {
        for (int c = 0; c < 2; ++c) {
            int r0 = wave * 32 + c * 16;
            gl_lds16(Xb + (size_t)(gm + r0 + arow) * CH + k0 + acol, &As[buf][r0][0]);
            gl_lds16(W  + (size_t)(gn + r0 + arow) * CH + k0 + acol, &Bs[buf][r0][0]);
        }
    };

    stage(0, 0);
    for (int kk = 0; kk < 32; ++kk) {
        int cur = kk & 1;
        __syncthreads();
        if (kk < 31) stage(cur ^ 1, (kk + 1) * 32);
        bf16x8 af[4], bfm[4];
        for (int i = 0; i < 4; i++)
            af[i] = *(const bf16x8*)&As[cur][wm * 64 + i * 16 + col][quad * 8];
        for (int j = 0; j < 4; j++)
            bfm[j] = *(const bf16x8*)&Bs[cur][wn * 64 + j * 16 + col][quad * 8];
        for (int i = 0; i < 4; i++)
            for (int j = 0; j < 4; j++)
                acc[i][j] = __builtin_amdgcn_mfma_f32_16x16x32_bf16(af[i], bfm[j], acc[i][j], 0, 0, 0);
    }

    __syncthreads();   // staging buffers dead; reuse LDS for epilogue tile

    const float* bias = (z == 0) ? bq : (z == 1) ? bk : bv;
    const int bb = gm >> 11, ss0 = gm & 2047;
    const int h0 = gn >> 6;          // block's n-range spans 2 heads

    if (z == 2) {
        // transpose tile into Ep[n_local][m_local]; m-contiguous r-values pack as b32
        for (int j = 0; j < 4; j++) {
            int nl = wn * 64 + j * 16 + col;
            float bias_v = bias[gn + nl];
            for (int i = 0; i < 4; i++) {
                int ml = wm * 64 + i * 16 + quad * 4;
                unsigned d0 = (unsigned)f2bf(acc[i][j][0] + bias_v) |
                              ((unsigned)f2bf(acc[i][j][1] + bias_v) << 16);
                unsigned d1 = (unsigned)f2bf(acc[i][j][2] + bias_v) |
                              ((unsigned)f2bf(acc[i][j][3] + bias_v) << 16);
                *(unsigned*)&Ep[nl][ml]     = d0;
                *(unsigned*)&Ep[nl][ml + 2] = d1;
            }
        }
        __syncthreads();
        for (int p = 0; p < 8; p++) {
            int nl = p * 16 + (tid >> 4);
            int seg = tid & 15;
            uint4 v = *(const uint4*)&Ep[nl][seg * 8];
            int h = h0 + (nl >> 6), d = nl & 63;
            *(uint4*)(Vt + ((size_t)(bb * CNH + h) * CDH + d) * CS + ss0 + seg * 8) = v;
        }
    } else {
        const float mulf = (z == 0) ? C_SC : 1.0f;
        for (int j = 0; j < 4; j++) {
            int nl = wn * 64 + j * 16 + col;
            float bias_v = bias[gn + nl];
            for (int i = 0; i < 4; i++)
                for (int r = 0; r < 4; r++) {
                    int ml = wm * 64 + i * 16 + quad * 4 + r;
                    Ep[ml][nl] = f2bf((acc[i][j][r] + bias_v) * mulf);
                }
        }
        __syncthreads();
        unsigned short* dst01 = (z == 0) ? Qo : Ko;
        for (int p = 0; p < 8; p++) {
            int ml = p * 16 + (tid >> 4);
            int half2 = (tid >> 3) & 1, seg = tid & 7;
            uint4 v = *(const uint4*)&Ep[ml][half2 * 64 + seg * 8];
            int h = h0 + half2;
            *(uint4*)(dst01 + ((size_t)(bb * CNH + h) * CS + ss0 + ml) * CDH + seg * 8) = v;
        }
    }
}

// ---------------- flash attention (R9-fallback-proven: dbuf + XCD pin) -------------
// grid: 512 blocks (8 q-blocks x 64 bh) x 256 threads = 4 waves x 64 q rows.
// Double-buffered K/V via global_load_lds, __syncthreads per iter (proven schedule),
// setprio pinning (load-bearing for correctness, R6/R7), XCD head-pinning
// (XCD c owns heads [8c,8c+8), 4 MB = its L2), swapped QK^T, in-register P
// redistribute (cvt_pk + permlane), static log2-domain softmax (Q pre-scaled).
// This body (as fallback in R9) measured fastest overall: total 236.6 µs.
__global__ __launch_bounds__(256, 2) void flash_attn_k(
    const unsigned short* __restrict__ Q,    // [B*h, S, d] (pre-scaled)
    const unsigned short* __restrict__ K,    // [B*h, S, d]
    const unsigned short* __restrict__ Vt,   // [B*h, d, S]
    const int* __restrict__ mask,            // [B, S]
    float* __restrict__ out)                 // [B, S, H]
{
    __shared__ alignas(16) unsigned short Ks[2][64][64];   // 16 KB
    __shared__ alignas(16) unsigned short Vs[2][64][64];   // 16 KB, [d][kv]
    __shared__ unsigned int Mbits[64];                     // 2048-bit mask

    const int tid  = threadIdx.x;
    const int wave = tid >> 6, lane = tid & 63;
    const int col = lane & 15, quad = lane >> 4;

    // XCD-aware bijective remap (512 wgs, 8 XCDs, launch order x-fastest)
    const int wg   = blockIdx.y * gridDim.x + blockIdx.x;
    const int nid  = (wg & 7) * 64 + (wg >> 3);
    const int bh   = nid >> 3;            // head index: XCD c gets heads [8c, 8c+8)
    const int qblk = nid & 7;
    const int bI = bh >> 4, hI = bh & 15;
    const int q0 = qblk * 256 + wave * 64;

    const unsigned short* Qp = Q  + (size_t)bh * CS * CDH;
    const unsigned short* Kp = K  + (size_t)bh * CS * CDH;
    const unsigned short* Vp = Vt + (size_t)bh * CDH * CS;

    // mask -> bitmask in LDS (first loop barrier publishes it)
    {
        const int* mg = mask + bI * CS;
        for (int j = 0; j < 8; j++) {
            int idx = wave * 512 + j * 64 + lane;
            unsigned long long bal = __ballot(mg[idx] != 0);
            if (lane == 0) {
                Mbits[wave * 16 + j * 2]     = (unsigned int)bal;
                Mbits[wave * 16 + j * 2 + 1] = (unsigned int)(bal >> 32);
            }
        }
    }

    // Q fragments in registers: frag[n=col][k=quad*8+j], 64 q rows per wave
    bf16x8 aq[4][2];
    for (int i = 0; i < 4; i++)
        for (int ks = 0; ks < 2; ks++)
            aq[i][ks] = *(const bf16x8*)(Qp + (size_t)(q0 + i * 16 + col) * CDH + ks * 32 + quad * 8);

    bf16x8 onesb;
    {
        union { unsigned short u; __bf16 b; } ob; ob.u = 0x3F80;  // bf16 1.0
        for (int j = 0; j < 8; j++) onesb[j] = ob.b;
    }

    f32x4 zero = {0.f, 0.f, 0.f, 0.f};
    f32x4 o[4][4], lfr[4];
    for (int i = 0; i < 4; i++) {
        lfr[i] = zero;
        for (int id = 0; id < 4; id++) o[i][id] = zero;
    }

    const int srow = lane >> 3;
    const int schk = (lane & 7) ^ srow;      // swizzled global chunk index

    auto stageKV = [&](int buf, int t) {
        const unsigned short* kg = Kp + (size_t)t * 64 * CDH;
        for (int c = 0; c < 2; c++) {
            int r0 = wave * 16 + c * 8;
            gl_lds16(kg + (size_t)(r0 + srow) * CDH + schk * 8, &Ks[buf][r0][0]);
            gl_lds16(Vp + (size_t)(r0 + srow) * CS + t * 64 + schk * 8, &Vs[buf][r0][0]);
        }
    };

    stageKV(0, 0);
    for (int kt = 0; kt < 32; ++kt) {
        int cur = kt & 1;
        __syncthreads();
        if (kt < 31) stageKV(cur ^ 1, kt + 1);

        // S'^T = (K Q^T) (log2-domain): sfr[i][ik][r] = S'[q=i*16+col][kv=ik*16+quad*4+r]
        f32x4 sfr[4][4];
        for (int i = 0; i < 4; i++) for (int ik = 0; ik < 4; ik++) sfr[i][ik] = zero;
        for (int ks = 0; ks < 2; ks++) {
            bf16x8 bkf[4];
            for (int ik = 0; ik < 4; ik++)
                bkf[ik] = *(const bf16x8*)&Ks[cur][ik * 16 + col][((ks * 4 + quad) ^ (col & 7)) * 8];
            __builtin_amdgcn_s_setprio(1);
            for (int i = 0; i < 4; i++)
                for (int ik = 0; ik < 4; ik++)
                    sfr[i][ik] = __builtin_amdgcn_mfma_f32_16x16x32_bf16(bkf[ik], aq[i][ks], sfr[i][ik], 0, 0, 0);
            __builtin_amdgcn_s_setprio(0);
        }

        // mask add only if some kv masked (uniform branch; all-ones in practice)
        unsigned int w0 = Mbits[kt * 2], w1 = Mbits[kt * 2 + 1];
        if ((w0 & w1) != 0xFFFFFFFFu) {
            for (int ik = 0; ik < 4; ik++)
                for (int r = 0; r < 4; r++) {
                    int kv = ik * 16 + quad * 4 + r;
                    unsigned bit = (kv < 32) ? (w0 >> kv) : (w1 >> (kv - 32));
                    float madd = (bit & 1u) ? 0.f : -1.0e30f;
                    for (int i = 0; i < 4; i++) sfr[i][ik][r] += madd;
                }
        }

        // V fragments hoisted (i-invariant): frag[n=col -> d][k=quad*8+j -> kv]
        bf16x8 bvf[2][4];
        for (int ks = 0; ks < 2; ks++)
            for (int id = 0; id < 4; id++)
                bvf[ks][id] = *(const bf16x8*)&Vs[cur][id * 16 + col][((ks * 4 + quad) ^ (col & 7)) * 8];

        // P = 2^(s'); pack to bf16 pairs, redistribute in-register into PV A-frags.
        for (int i = 0; i < 4; i++) {
            unsigned c[4][2];
            for (int ik = 0; ik < 4; ik++)
                for (int h = 0; h < 2; h++)
                    c[ik][h] = cvtpk_bf16(fexp2(sfr[i][ik][2 * h]), fexp2(sfr[i][ik][2 * h + 1]));

            unsigned a0 = c[0][0], b0 = c[1][0]; pl32swap(a0, b0); pl16swap(a0, b0); // ap0.dw0, ap0.dw2
            unsigned a1 = c[0][1], b1 = c[1][1]; pl32swap(a1, b1); pl16swap(a1, b1); // ap0.dw1, ap0.dw3
            unsigned a2 = c[2][0], b2 = c[3][0]; pl32swap(a2, b2); pl16swap(a2, b2); // ap1.dw0, ap1.dw2
            unsigned a3 = c[2][1], b3 = c[3][1]; pl32swap(a3, b3); pl16swap(a3, b3); // ap1.dw1, ap1.dw3

            uint4 lo4; lo4.x = a0; lo4.y = a1; lo4.z = b0; lo4.w = b1;
            uint4 hi4; hi4.x = a2; hi4.y = a3; hi4.z = b2; hi4.w = b3;
            bf16x8 ap0, ap1;
            __builtin_memcpy(&ap0, &lo4, 16);
            __builtin_memcpy(&ap1, &hi4, 16);

            __builtin_amdgcn_s_setprio(1);
            for (int id = 0; id < 4; id++)
                o[i][id] = __builtin_amdgcn_mfma_f32_16x16x32_bf16(ap0, bvf[0][id], o[i][id], 0, 0, 0);
            lfr[i] = __builtin_amdgcn_mfma_f32_16x16x32_bf16(ap0, onesb, lfr[i], 0, 0, 0);
            for (int id = 0; id < 4; id++)
                o[i][id] = __builtin_amdgcn_mfma_f32_16x16x32_bf16(ap1, bvf[1][id], o[i][id], 0, 0, 0);
            lfr[i] = __builtin_amdgcn_mfma_f32_16x16x32_bf16(ap1, onesb, lfr[i], 0, 0, 0);
            __builtin_amdgcn_s_setprio(0);
        }
    }

    // epilogue: out[b][s][h*64+d] = O / l
    for (int i = 0; i < 4; i++)
        for (int r = 0; r < 4; r++) {
            int sI = q0 + i * 16 + quad * 4 + r;
            float inv = 1.0f / lfr[i][r];
            for (int id = 0; id < 4; id++)
                out[((size_t)(bI * CS + sI)) * CH + hI * CDH + id * 16 + col] = o[i][id][r] * inv;
        }
}

extern "C" void kernel_launch(void* const* d_in, const int* in_sizes, int n_in,
                              void* d_out, int out_size, void* d_ws, size_t ws_size,
                              hipStream_t stream) {
    const float* hs  = (const float*)d_in[0];
    const int*  mask = (const int*)d_in[1];
    const float* Wq  = (const float*)d_in[2];
    const float* bq  = (const float*)d_in[3];
    const float* Wk  = (const float*)d_in[4];
    const float* bk  = (const float*)d_in[5];
    const float* Wv  = (const float*)d_in[6];
    const float* bv  = (const float*)d_in[7];
    float* out = (float*)d_out;

    char* ws = (char*)d_ws;
    unsigned short* Xb = (unsigned short*)(ws);                    // 16 MB
    unsigned short* Wb = (unsigned short*)(ws + 16777216);         // 6 MB
    unsigned short* Qb = (unsigned short*)(ws + 23068672);         // 16 MB
    unsigned short* Kb = (unsigned short*)(ws + 39845888);         // 16 MB
    unsigned short* Vt = (unsigned short*)(ws + 56623104);         // 16 MB

    cvt_all_k<<<dim3(11264), 256, 0, stream>>>(hs, Wq, Wk, Wv, Xb, Wb);

    qkv_gemm_k<<<dim3(64, 8, 3), 256, 0, stream>>>(Xb, Wb, bq, bk, bv, Qb, Kb, Vt);

    flash_attn_k<<<dim3(8, 64), 256, 0, stream>>>(Qb, Kb, Vt, mask, out);
}

// Round 11
// 242.128 us; speedup vs baseline: 1.0078x; 1.0078x over previous
//
#include <hip/hip_runtime.h>
#include <hip/hip_bf16.h>
#include <stdint.h>

// Problem constants
constexpr int CB  = 4;     // batch
constexpr int CS  = 2048;  // seq len
constexpr int CH  = 1024;  // hidden
constexpr int CNH = 16;    // heads
constexpr int CDH = 64;    // head dim
constexpr int CM  = CB * CS;  // 8192 rows

typedef __bf16 bf16x8 __attribute__((ext_vector_type(8)));
typedef float  f32x4  __attribute__((ext_vector_type(4)));

// round-to-nearest-even f32 -> bf16 (bit pattern)
__device__ __forceinline__ unsigned short f2bf(float f) {
    union { float f; unsigned u; } c; c.f = f;
    unsigned u = c.u;
    unsigned r = (u + 0x7fffu + ((u >> 16) & 1u)) >> 16;
    return (unsigned short)r;
}

// async global->LDS, 16B per lane. LDS dest = base + lane*16 (wave-uniform base).
__device__ __forceinline__ void gl_lds16(const void* g, void* l) {
    __builtin_amdgcn_global_load_lds((const __attribute__((address_space(1))) uint32_t*)g,
                                     (__attribute__((address_space(3))) uint32_t*)l,
                                     16, 0, 0);
}

__device__ __forceinline__ float fexp2(float x) {
#if __has_builtin(__builtin_amdgcn_exp2f)
    return __builtin_amdgcn_exp2f(x);
#else
    return exp2f(x);
#endif
}

// pack two f32 -> one dword of 2 bf16 (RNE). No builtin on gfx950 (m240) -> asm.
__device__ __forceinline__ unsigned cvtpk_bf16(float lo, float hi) {
    unsigned r;
    asm("v_cvt_pk_bf16_f32 %0, %1, %2" : "=v"(r) : "v"(lo), "v"(hi));
    return r;
}

// a' = [a_r0, a_r1, b_r0, b_r1]; b' = [a_r2, a_r3, b_r2, b_r3]  (16-lane rows)
__device__ __forceinline__ void pl32swap(unsigned &a, unsigned &b) {
#if __has_builtin(__builtin_amdgcn_permlane32_swap)
    auto r = __builtin_amdgcn_permlane32_swap(a, b, false, false);
    a = r[0]; b = r[1];
#else
    int lane = threadIdx.x & 63;
    unsigned as = (unsigned)__shfl((int)a, lane ^ 32);
    unsigned bs = (unsigned)__shfl((int)b, lane ^ 32);
    unsigned na = (lane < 32) ? a : bs;
    unsigned nb = (lane < 32) ? as : b;
    a = na; b = nb;
#endif
}

// a' = [a_r0, b_r0, a_r2, b_r2]; b' = [a_r1, b_r1, a_r3, b_r3]
__device__ __forceinline__ void pl16swap(unsigned &a, unsigned &b) {
#if __has_builtin(__builtin_amdgcn_permlane16_swap)
    auto r = __builtin_amdgcn_permlane16_swap(a, b, false, false);
    a = r[0]; b = r[1];
#else
    unsigned as = __builtin_amdgcn_ds_swizzle(a, 0x401F);  // lane ^ 16 within 32-halves
    unsigned bs = __builtin_amdgcn_ds_swizzle(b, 0x401F);
    int odd = (threadIdx.x >> 4) & 1;
    unsigned na = odd ? bs : a;
    unsigned nb = odd ? b : as;
    a = na; b = nb;
#endif
}

// 1/sqrt(dh) * log2(e): folded into Q at projection time
constexpr float C_SC = 0.125f * 1.44269504f;

// ---------------- fp32 -> bf16 convert (X + 3 weights, one launch) ----------------
// exact 1-D grid: 8192 blocks for X, 1024 per weight; one float4 per thread.
__global__ __launch_bounds__(256) void cvt_all_k(const float* __restrict__ hs,
                                                 const float* __restrict__ w0,
                                                 const float* __restrict__ w1,
                                                 const float* __restrict__ w2,
                                                 unsigned short* __restrict__ Xb,
                                                 unsigned short* __restrict__ Wb) {
    int b = blockIdx.x;
    const float* src; unsigned short* dst; int i;
    if (b < 8192) {
        src = hs; dst = Xb;
        i = b * 256 + (int)threadIdx.x;            // < CM*CH/4 exactly
    } else {
        int t = b - 8192;
        int z = t >> 10;                           // 0,1,2
        src = (z == 0) ? w0 : (z == 1) ? w1 : w2;
        dst = Wb + z * CH * CH;
        i = (t & 1023) * 256 + (int)threadIdx.x;   // < CH*CH/4 exactly
    }
    float4 v = ((const float4*)src)[i];
    ushort4 o;
    o.x = f2bf(v.x); o.y = f2bf(v.y); o.z = f2bf(v.z); o.w = f2bf(v.w);
    ((ushort4*)dst)[i] = o;
}

// ---------------- fused QKV projection GEMM (pipelined + LDS-repacked epilogue) ----
// C[m,n] = sum_k X[m,k] * W[n,k] + bias[n]
// z=0 (Q): out [b,h,s,d], pre-scaled by C_SC. z=1 (K): [b,h,s,d]. z=2 (V): [b,h,d,s].
__global__ __launch_bounds__(256) void qkv_gemm_k(
    const unsigned short* __restrict__ Xb,
    const unsigned short* __restrict__ Wb,
    const float* __restrict__ bq, const float* __restrict__ bk, const float* __restrict__ bv,
    unsigned short* __restrict__ Qo,
    unsigned short* __restrict__ Ko,
    unsigned short* __restrict__ Vt)
{
    // staging (32 KB, double-buffered) and epilogue tile (34 KB) alias the same LDS
    __shared__ alignas(16) unsigned char smem[34816];
    typedef unsigned short (*tile_t)[128][32];
    tile_t As = (tile_t)smem;                 // [2][128][32]
    tile_t Bs = (tile_t)(smem + 16384);       // [2][128][32]
    typedef unsigned short (*ep_t)[136];      // [128][136] (pad -> 16B-aligned rows)
    ep_t Ep = (ep_t)smem;

    const int tid  = threadIdx.x;
    const int wave = tid >> 6, lane = tid & 63;
    const int wm = wave >> 1, wn = wave & 1;
    const int col = lane & 15, quad = lane >> 4;
    const int gm = blockIdx.x * 128, gn = blockIdx.y * 128;
    const int z  = blockIdx.z;
    const unsigned short* W = Wb + (size_t)z * CH * CH;

    f32x4 zero = {0.f, 0.f, 0.f, 0.f};
    f32x4 acc[4][4];
    for (int i = 0; i < 4; i++) for (int j = 0; j < 4; j++) acc[i][j] = zero;

    const int arow = lane >> 2;
    const int acol = (lane & 3) * 8;

    auto stage = [&](int buf, int k0) {
        for (int c = 0; c < 2; ++c) {
            int r0 = wave * 32 + c * 16;
            gl_lds16(Xb + (size_t)(gm + r0 + arow) * CH + k0 + acol, &As[buf][r0][0]);
            gl_lds16(W  + (size_t)(gn + r0 + arow) * CH + k0 + acol, &Bs[buf][r0][0]);
        }
    };

    stage(0, 0);
    for (int kk = 0; kk < 32; ++kk) {
        int cur = kk & 1;
        __syncthreads();
        if (kk < 31) stage(cur ^ 1, (kk + 1) * 32);
        bf16x8 af[4], bfm[4];
        for (int i = 0; i < 4; i++)
            af[i] = *(const bf16x8*)&As[cur][wm * 64 + i * 16 + col][quad * 8];
        for (int j = 0; j < 4; j++)
            bfm[j] = *(const bf16x8*)&Bs[cur][wn * 64 + j * 16 + col][quad * 8];
        for (int i = 0; i < 4; i++)
            for (int j = 0; j < 4; j++)
                acc[i][j] = __builtin_amdgcn_mfma_f32_16x16x32_bf16(af[i], bfm[j], acc[i][j], 0, 0, 0);
    }

    __syncthreads();   // staging buffers dead; reuse LDS for epilogue tile

    const float* bias = (z == 0) ? bq : (z == 1) ? bk : bv;
    const int bb = gm >> 11, ss0 = gm & 2047;
    const int h0 = gn >> 6;          // block's n-range spans 2 heads

    if (z == 2) {
        // transpose tile into Ep[n_local][m_local]; m-contiguous r-values pack as b32
        for (int j = 0; j < 4; j++) {
            int nl = wn * 64 + j * 16 + col;
            float bias_v = bias[gn + nl];
            for (int i = 0; i < 4; i++) {
                int ml = wm * 64 + i * 16 + quad * 4;
                unsigned d0 = (unsigned)f2bf(acc[i][j][0] + bias_v) |
                              ((unsigned)f2bf(acc[i][j][1] + bias_v) << 16);
                unsigned d1 = (unsigned)f2bf(acc[i][j][2] + bias_v) |
                              ((unsigned)f2bf(acc[i][j][3] + bias_v) << 16);
                *(unsigned*)&Ep[nl][ml]     = d0;
                *(unsigned*)&Ep[nl][ml + 2] = d1;
            }
        }
        __syncthreads();
        for (int p = 0; p < 8; p++) {
            int nl = p * 16 + (tid >> 4);
            int seg = tid & 15;
            uint4 v = *(const uint4*)&Ep[nl][seg * 8];
            int h = h0 + (nl >> 6), d = nl & 63;
            *(uint4*)(Vt + ((size_t)(bb * CNH + h) * CDH + d) * CS + ss0 + seg * 8) = v;
        }
    } else {
        const float mulf = (z == 0) ? C_SC : 1.0f;
        for (int j = 0; j < 4; j++) {
            int nl = wn * 64 + j * 16 + col;
            float bias_v = bias[gn + nl];
            for (int i = 0; i < 4; i++)
                for (int r = 0; r < 4; r++) {
                    int ml = wm * 64 + i * 16 + quad * 4 + r;
                    Ep[ml][nl] = f2bf((acc[i][j][r] + bias_v) * mulf);
                }
        }
        __syncthreads();
        unsigned short* dst01 = (z == 0) ? Qo : Ko;
        for (int p = 0; p < 8; p++) {
            int ml = p * 16 + (tid >> 4);
            int half2 = (tid >> 3) & 1, seg = tid & 7;
            uint4 v = *(const uint4*)&Ep[ml][half2 * 64 + seg * 8];
            int h = h0 + half2;
            *(uint4*)(dst01 + ((size_t)(bb * CNH + h) * CS + ss0 + ml) * CDH + seg * 8) = v;
        }
    }
}

// ---------------- flash attention: dbuf + XCD pin + ANTI-PHASE STAGGER -------------
// grid: 512 blocks (8 q-blocks x 64 bh) x 256 threads = 4 waves x 64 q rows.
// R10 body unchanged EXCEPT: blocks with (wg>>8)&1==1 sleep ~3300 cy once before
// staging. Rationale: each SIMD hosts 2 waves from the 2 co-resident blocks
// (wg, wg+256 under round-robin dispatch). Both run the identical periodic loop
// launched simultaneously -> phase-locked: MFMA bursts align, VALU bursts align,
// pipes serialize (R10: MfmaUtil 35.5 + VALUBusy 41.6 = 77% ~= sum-of-pipes/wall,
// i.e. ~0 overlap). A one-time half-period (6480/2 cy) delay puts pairs in
// anti-phase: A's QK MFMA overlaps B's softmax VALU. Pure delay -> zero
// correctness risk; jitter drift over 32 iters (~60 cy) << half-period.
__global__ __launch_bounds__(256, 2) void flash_attn_k(
    const unsigned short* __restrict__ Q,    // [B*h, S, d] (pre-scaled)
    const unsigned short* __restrict__ K,    // [B*h, S, d]
    const unsigned short* __restrict__ Vt,   // [B*h, d, S]
    const int* __restrict__ mask,            // [B, S]
    float* __restrict__ out)                 // [B, S, H]
{
    __shared__ alignas(16) unsigned short Ks[2][64][64];   // 16 KB
    __shared__ alignas(16) unsigned short Vs[2][64][64];   // 16 KB, [d][kv]
    __shared__ unsigned int Mbits[64];                     // 2048-bit mask

    const int tid  = threadIdx.x;
    const int wave = tid >> 6, lane = tid & 63;
    const int col = lane & 15, quad = lane >> 4;

    // XCD-aware bijective remap (512 wgs, 8 XCDs, launch order x-fastest)
    const int wg   = blockIdx.y * gridDim.x + blockIdx.x;
    const int nid  = (wg & 7) * 64 + (wg >> 3);
    const int bh   = nid >> 3;            // head index: XCD c gets heads [8c, 8c+8)
    const int qblk = nid & 7;
    const int bI = bh >> 4, hI = bh & 15;
    const int q0 = qblk * 256 + wave * 64;

    const unsigned short* Qp = Q  + (size_t)bh * CS * CDH;
    const unsigned short* Kp = K  + (size_t)bh * CS * CDH;
    const unsigned short* Vp = Vt + (size_t)bh * CDH * CS;

    // mask -> bitmask in LDS (first loop barrier publishes it)
    {
        const int* mg = mask + bI * CS;
        for (int j = 0; j < 8; j++) {
            int idx = wave * 512 + j * 64 + lane;
            unsigned long long bal = __ballot(mg[idx] != 0);
            if (lane == 0) {
                Mbits[wave * 16 + j * 2]     = (unsigned int)bal;
                Mbits[wave * 16 + j * 2 + 1] = (unsigned int)(bal >> 32);
            }
        }
    }

    // Q fragments in registers: frag[n=col][k=quad*8+j], 64 q rows per wave
    bf16x8 aq[4][2];
    for (int i = 0; i < 4; i++)
        for (int ks = 0; ks < 2; ks++)
            aq[i][ks] = *(const bf16x8*)(Qp + (size_t)(q0 + i * 16 + col) * CDH + ks * 32 + quad * 8);

    bf16x8 onesb;
    {
        union { unsigned short u; __bf16 b; } ob; ob.u = 0x3F80;  // bf16 1.0
        for (int j = 0; j < 8; j++) onesb[j] = ob.b;
    }

    f32x4 zero = {0.f, 0.f, 0.f, 0.f};
    f32x4 o[4][4], lfr[4];
    for (int i = 0; i < 4; i++) {
        lfr[i] = zero;
        for (int id = 0; id < 4; id++) o[i][id] = zero;
    }

    // anti-phase stagger: second dispatch round sleeps ~half an iteration (once)
    if ((wg >> 8) & 1) {
#if __has_builtin(__builtin_amdgcn_s_sleep)
        __builtin_amdgcn_s_sleep(13);
        __builtin_amdgcn_s_sleep(13);
        __builtin_amdgcn_s_sleep(13);
        __builtin_amdgcn_s_sleep(13);
#else
        for (int d = 0; d < 400; d++) asm volatile("s_nop 7");
#endif
    }

    const int srow = lane >> 3;
    const int schk = (lane & 7) ^ srow;      // swizzled global chunk index

    auto stageKV = [&](int buf, int t) {
        const unsigned short* kg = Kp + (size_t)t * 64 * CDH;
        for (int c = 0; c < 2; c++) {
            int r0 = wave * 16 + c * 8;
            gl_lds16(kg + (size_t)(r0 + srow) * CDH + schk * 8, &Ks[buf][r0][0]);
            gl_lds16(Vp + (size_t)(r0 + srow) * CS + t * 64 + schk * 8, &Vs[buf][r0][0]);
        }
    };

    stageKV(0, 0);
    for (int kt = 0; kt < 32; ++kt) {
        int cur = kt & 1;
        __syncthreads();
        if (kt < 31) stageKV(cur ^ 1, kt + 1);

        // S'^T = (K Q^T) (log2-domain): sfr[i][ik][r] = S'[q=i*16+col][kv=ik*16+quad*4+r]
        f32x4 sfr[4][4];
        for (int i = 0; i < 4; i++) for (int ik = 0; ik < 4; ik++) sfr[i][ik] = zero;
        for (int ks = 0; ks < 2; ks++) {
            bf16x8 bkf[4];
            for (int ik = 0; ik < 4; ik++)
                bkf[ik] = *(const bf16x8*)&Ks[cur][ik * 16 + col][((ks * 4 + quad) ^ (col & 7)) * 8];
            __builtin_amdgcn_s_setprio(1);
            for (int i = 0; i < 4; i++)
                for (int ik = 0; ik < 4; ik++)
                    sfr[i][ik] = __builtin_amdgcn_mfma_f32_16x16x32_bf16(bkf[ik], aq[i][ks], sfr[i][ik], 0, 0, 0);
            __builtin_amdgcn_s_setprio(0);
        }

        // mask add only if some kv masked (uniform branch; all-ones in practice)
        unsigned int w0 = Mbits[kt * 2], w1 = Mbits[kt * 2 + 1];
        if ((w0 & w1) != 0xFFFFFFFFu) {
            for (int ik = 0; ik < 4; ik++)
                for (int r = 0; r < 4; r++) {
                    int kv = ik * 16 + quad * 4 + r;
                    unsigned bit = (kv < 32) ? (w0 >> kv) : (w1 >> (kv - 32));
                    float madd = (bit & 1u) ? 0.f : -1.0e30f;
                    for (int i = 0; i < 4; i++) sfr[i][ik][r] += madd;
                }
        }

        // V fragments hoisted (i-invariant): frag[n=col -> d][k=quad*8+j -> kv]
        bf16x8 bvf[2][4];
        for (int ks = 0; ks < 2; ks++)
            for (int id = 0; id < 4; id++)
                bvf[ks][id] = *(const bf16x8*)&Vs[cur][id * 16 + col][((ks * 4 + quad) ^ (col & 7)) * 8];

        // P = 2^(s'); pack to bf16 pairs, redistribute in-register into PV A-frags.
        for (int i = 0; i < 4; i++) {
            unsigned c[4][2];
            for (int ik = 0; ik < 4; ik++)
                for (int h = 0; h < 2; h++)
                    c[ik][h] = cvtpk_bf16(fexp2(sfr[i][ik][2 * h]), fexp2(sfr[i][ik][2 * h + 1]));

            unsigned a0 = c[0][0], b0 = c[1][0]; pl32swap(a0, b0); pl16swap(a0, b0); // ap0.dw0, ap0.dw2
            unsigned a1 = c[0][1], b1 = c[1][1]; pl32swap(a1, b1); pl16swap(a1, b1); // ap0.dw1, ap0.dw3
            unsigned a2 = c[2][0], b2 = c[3][0]; pl32swap(a2, b2); pl16swap(a2, b2); // ap1.dw0, ap1.dw2
            unsigned a3 = c[2][1], b3 = c[3][1]; pl32swap(a3, b3); pl16swap(a3, b3); // ap1.dw1, ap1.dw3

            uint4 lo4; lo4.x = a0; lo4.y = a1; lo4.z = b0; lo4.w = b1;
            uint4 hi4; hi4.x = a2; hi4.y = a3; hi4.z = b2; hi4.w = b3;
            bf16x8 ap0, ap1;
            __builtin_memcpy(&ap0, &lo4, 16);
            __builtin_memcpy(&ap1, &hi4, 16);

            __builtin_amdgcn_s_setprio(1);
            for (int id = 0; id < 4; id++)
                o[i][id] = __builtin_amdgcn_mfma_f32_16x16x32_bf16(ap0, bvf[0][id], o[i][id], 0, 0, 0);
            lfr[i] = __builtin_amdgcn_mfma_f32_16x16x32_bf16(ap0, onesb, lfr[i], 0, 0, 0);
            for (int id = 0; id < 4; id++)
                o[i][id] = __builtin_amdgcn_mfma_f32_16x16x32_bf16(ap1, bvf[1][id], o[i][id], 0, 0, 0);
            lfr[i] = __builtin_amdgcn_mfma_f32_16x16x32_bf16(ap1, onesb, lfr[i], 0, 0, 0);
            __builtin_amdgcn_s_setprio(0);
        }
    }

    // epilogue: out[b][s][h*64+d] = O / l
    for (int i = 0; i < 4; i++)
        for (int r = 0; r < 4; r++) {
            int sI = q0 + i * 16 + quad * 4 + r;
            float inv = 1.0f / lfr[i][r];
            for (int id = 0; id < 4; id++)
                out[((size_t)(bI * CS + sI)) * CH + hI * CDH + id * 16 + col] = o[i][id][r] * inv;
        }
}

extern "C" void kernel_launch(void* const* d_in, const int* in_sizes, int n_in,
                              void* d_out, int out_size, void* d_ws, size_t ws_size,
                              hipStream_t stream) {
    const float* hs  = (const float*)d_in[0];
    const int*  mask = (const int*)d_in[1];
    const float* Wq  = (const float*)d_in[2];
    const float* bq  = (const float*)d_in[3];
    const float* Wk  = (const float*)d_in[4];
    const float* bk  = (const float*)d_in[5];
    const float* Wv  = (const float*)d_in[6];
    const float* bv  = (const float*)d_in[7];
    float* out = (float*)d_out;

    char* ws = (char*)d_ws;
    unsigned short* Xb = (unsigned short*)(ws);                    // 16 MB
    unsigned short* Wb = (unsigned short*)(ws + 16777216);         // 6 MB
    unsigned short* Qb = (unsigned short*)(ws + 23068672);         // 16 MB
    unsigned short* Kb = (unsigned short*)(ws + 39845888);         // 16 MB
    unsigned short* Vt = (unsigned short*)(ws + 56623104);         // 16 MB

    cvt_all_k<<<dim3(11264), 256, 0, stream>>>(hs, Wq, Wk, Wv, Xb, Wb);

    qkv_gemm_k<<<dim3(64, 8, 3), 256, 0, stream>>>(Xb, Wb, bq, bk, bv, Qb, Kb, Vt);

    flash_attn_k<<<dim3(8, 64), 256, 0, stream>>>(Qb, Kb, Vt, mask, out);
}